// Round 8
// baseline (1156.186 us; speedup 1.0000x reference)
//
#include <hip/hip_runtime.h>
#include <hip/hip_bf16.h>
#include <stdint.h>

#define TOKENS 8192
#define DIM 2048
#define EXPERTS 64
#define CAP 256
#define COMB_ELEMS ((size_t)TOKENS * EXPERTS * CAP)  // 134217728
#define OUT_ELEMS (1 + 2 * COMB_ELEMS)               // 268435457

#define GEMM_BLOCKS 256
#define FILL_BLOCKS 2048

typedef float f32x4 __attribute__((ext_vector_type(4)));

// ---------------- threefry2x32 (exact JAX semantics) ----------------
__device__ __forceinline__ void tf_round(uint32_t& a, uint32_t& b, int r) {
  a += b;
  b = (b << r) | (b >> (32 - r));
  b ^= a;
}

__device__ __forceinline__ void threefry2x32(uint32_t k0, uint32_t k1,
                                             uint32_t x0, uint32_t x1,
                                             uint32_t& o0, uint32_t& o1) {
  const uint32_t ks0 = k0, ks1 = k1, ks2 = k0 ^ k1 ^ 0x1BD11BDAu;
  x0 += ks0; x1 += ks1;
  tf_round(x0, x1, 13); tf_round(x0, x1, 15); tf_round(x0, x1, 26); tf_round(x0, x1, 6);
  x0 += ks1; x1 += ks2 + 1u;
  tf_round(x0, x1, 17); tf_round(x0, x1, 29); tf_round(x0, x1, 16); tf_round(x0, x1, 24);
  x0 += ks2; x1 += ks0 + 2u;
  tf_round(x0, x1, 13); tf_round(x0, x1, 15); tf_round(x0, x1, 26); tf_round(x0, x1, 6);
  x0 += ks0; x1 += ks1 + 3u;
  tf_round(x0, x1, 17); tf_round(x0, x1, 29); tf_round(x0, x1, 16); tf_round(x0, x1, 24);
  x0 += ks1; x1 += ks2 + 4u;
  tf_round(x0, x1, 13); tf_round(x0, x1, 15); tf_round(x0, x1, 26); tf_round(x0, x1, 6);
  x0 += ks2; x1 += ks0 + 5u;
  o0 = x0; o1 = x1;
}

// ---------------- K1: GEMM (32 tok x 64 exp, BK=32) + gate epilogue ----------
__global__ __launch_bounds__(256) void k_gemm_gate(const float* __restrict__ x,
    const float* __restrict__ wg,
    int* __restrict__ e1, int* __restrict__ e2,
    float* __restrict__ g1, float* __restrict__ g2,
    float* __restrict__ gpart) {
  __shared__ float xs[32][33];     // [token][k]
  __shared__ float wt[32][64];     // [k][expert] transposed; reused as score[t][e]
  __shared__ float gpl[4][64];     // per-wave gate column partials

  const int tid = threadIdx.x;
  const int tok0 = blockIdx.x * 32;
  const int e0 = (tid & 15) * 4;
  const int t0 = (tid >> 4) * 2;

  const int xr = tid >> 3;
  const int xc = (tid & 7) << 2;
  const int wr = tid >> 2;
  const int wc = (tid & 3) << 3;

  const float* xp = x + (size_t)(tok0 + xr) * DIM + xc;
  const float* wp = wg + (size_t)wr * DIM + wc;

  float4 xv  = *reinterpret_cast<const float4*>(xp);
  float4 wv0 = *reinterpret_cast<const float4*>(wp);
  float4 wv1 = *reinterpret_cast<const float4*>(wp + 4);

  float acc[2][4] = {{0.f, 0.f, 0.f, 0.f}, {0.f, 0.f, 0.f, 0.f}};

  for (int k0 = 0; k0 < DIM; k0 += 32) {
    *reinterpret_cast<float4*>(&xs[xr][xc]) = xv;
    wt[wc + 0][wr] = wv0.x; wt[wc + 1][wr] = wv0.y;
    wt[wc + 2][wr] = wv0.z; wt[wc + 3][wr] = wv0.w;
    wt[wc + 4][wr] = wv1.x; wt[wc + 5][wr] = wv1.y;
    wt[wc + 6][wr] = wv1.z; wt[wc + 7][wr] = wv1.w;
    __syncthreads();
    if (k0 + 32 < DIM) {
      xv  = *reinterpret_cast<const float4*>(xp + k0 + 32);
      wv0 = *reinterpret_cast<const float4*>(wp + k0 + 32);
      wv1 = *reinterpret_cast<const float4*>(wp + k0 + 36);
    }
#pragma unroll
    for (int kk = 0; kk < 32; ++kk) {
      const float4 b = *reinterpret_cast<const float4*>(&wt[kk][e0]);
      const float a0 = xs[t0][kk];
      const float a1 = xs[t0 + 1][kk];
      acc[0][0] = fmaf(a0, b.x, acc[0][0]);
      acc[0][1] = fmaf(a0, b.y, acc[0][1]);
      acc[0][2] = fmaf(a0, b.z, acc[0][2]);
      acc[0][3] = fmaf(a0, b.w, acc[0][3]);
      acc[1][0] = fmaf(a1, b.x, acc[1][0]);
      acc[1][1] = fmaf(a1, b.y, acc[1][1]);
      acc[1][2] = fmaf(a1, b.z, acc[1][2]);
      acc[1][3] = fmaf(a1, b.w, acc[1][3]);
    }
    __syncthreads();
  }

#pragma unroll
  for (int i = 0; i < 2; ++i)
    *reinterpret_cast<float4*>(&wt[t0 + i][e0]) =
        make_float4(acc[i][0], acc[i][1], acc[i][2], acc[i][3]);
  __syncthreads();

  const int w = tid >> 6;
  const int lane = tid & 63;
  float colsum = 0.f;
  for (int lt = w * 8; lt < w * 8 + 8; ++lt) {
    const int t = tok0 + lt;
    const float logit = wt[lt][lane];

    float m = logit;
#pragma unroll
    for (int off = 32; off > 0; off >>= 1) m = fmaxf(m, __shfl_xor(m, off));
    const float ex = expf(logit - m);
    float s = ex;
#pragma unroll
    for (int off = 32; off > 0; off >>= 1) s += __shfl_xor(s, off);
    const float gate = ex / s;
    colsum += gate;

    float v1 = logit; int i1 = lane;
#pragma unroll
    for (int off = 32; off > 0; off >>= 1) {
      const float ov = __shfl_xor(v1, off);
      const int oi = __shfl_xor(i1, off);
      if (ov > v1 || (ov == v1 && oi < i1)) { v1 = ov; i1 = oi; }
    }

    // gumbel(key=42), jax_threefry_partitionable: counter=(0,i), bits=o0^o1
    const uint32_t i_flat = (uint32_t)t * 64u + (uint32_t)lane;
    uint32_t b0, b1;
    threefry2x32(0u, 42u, 0u, i_flat, b0, b1);
    const uint32_t bits = b0 ^ b1;
    float u = __uint_as_float((bits >> 9) | 0x3f800000u) - 1.0f;
    u += 1.17549435e-38f;
    const float gum = -logf(-logf(u));
    const float noisy = (lane == i1) ? -__builtin_inff() : (logit + gum);

    float v2 = noisy; int i2 = lane;
#pragma unroll
    for (int off = 32; off > 0; off >>= 1) {
      const float ov = __shfl_xor(v2, off);
      const int oi = __shfl_xor(i2, off);
      if (ov > v2 || (ov == v2 && oi < i2)) { v2 = ov; i2 = oi; }
    }

    const float gate1 = __shfl(gate, i1);
    const float gate2 = __shfl(gate, i2);
    if (lane == 0) { e1[t] = i1; e2[t] = i2; g1[t] = gate1; g2[t] = gate2; }
  }
  gpl[w][lane] = colsum;
  __syncthreads();
  if (w == 0)
    gpart[(size_t)blockIdx.x * 64 + lane] =
        (gpl[0][lane] + gpl[1][lane]) + (gpl[2][lane] + gpl[3][lane]);
}

// ---------------- K2: per-expert prefix ranks (3-sync) + gsum ----------------
__global__ __launch_bounds__(256) void k_scan(const int* __restrict__ e1,
    const int* __restrict__ e2, const float* __restrict__ gpart,
    int* __restrict__ loc1, int* __restrict__ loc2,
    int* __restrict__ counts1, float* __restrict__ gsum) {
  const int e = blockIdx.x;
  const int tid = threadIdx.x;
  const int lane = tid & 63;
  const int w = tid >> 6;
  __shared__ int wt1[32][4], wt2[32][4];
  __shared__ int pre1[32][4], pre2[32][4];
  __shared__ int c1tot;
  __shared__ float gw[4];

  float gp = gpart[(size_t)tid * 64 + e];
#pragma unroll
  for (int off = 32; off > 0; off >>= 1) gp += __shfl_xor(gp, off);
  if (lane == 0) gw[w] = gp;

  const uint64_t ltm = (lane == 0) ? 0ull : ((~0ull) >> (64 - lane));

  int r1[32], r2[32];
#pragma unroll
  for (int s = 0; s < 32; ++s) {
    const int t = s * 256 + tid;
    const bool q1 = (e1[t] == e);
    const bool q2 = (e2[t] == e);
    const uint64_t m1 = __ballot(q1);
    const uint64_t m2 = __ballot(q2);
    r1[s] = q1 ? (int)__popcll(m1 & ltm) + 1 : 0;
    r2[s] = q2 ? (int)__popcll(m2 & ltm) + 1 : 0;
    if (lane == 0) { wt1[s][w] = (int)__popcll(m1); wt2[s][w] = (int)__popcll(m2); }
  }
  __syncthreads();

  if (tid == 0) gsum[e] = (gw[0] + gw[1]) + (gw[2] + gw[3]);

  if (w == 0) {
    {
      int va = wt1[lane >> 2][lane & 3];
      int vb = wt1[(64 + lane) >> 2][(64 + lane) & 3];
      int sa = va, sb = vb;
#pragma unroll
      for (int d = 1; d < 64; d <<= 1) {
        const int t1 = __shfl_up(sa, d);
        const int t2 = __shfl_up(sb, d);
        if (lane >= d) { sa += t1; sb += t2; }
      }
      const int tot_a = __shfl(sa, 63);
      pre1[lane >> 2][lane & 3] = sa - va;
      pre1[(64 + lane) >> 2][(64 + lane) & 3] = tot_a + sb - vb;
      if (lane == 63) c1tot = tot_a + sb;
    }
    {
      int va = wt2[lane >> 2][lane & 3];
      int vb = wt2[(64 + lane) >> 2][(64 + lane) & 3];
      int sa = va, sb = vb;
#pragma unroll
      for (int d = 1; d < 64; d <<= 1) {
        const int t1 = __shfl_up(sa, d);
        const int t2 = __shfl_up(sb, d);
        if (lane >= d) { sa += t1; sb += t2; }
      }
      const int tot_a = __shfl(sa, 63);
      pre2[lane >> 2][lane & 3] = sa - va;
      pre2[(64 + lane) >> 2][(64 + lane) & 3] = tot_a + sb - vb;
    }
  }
  __syncthreads();

  const int c1 = c1tot;
  if (tid == 0) counts1[e] = c1;

#pragma unroll
  for (int s = 0; s < 32; ++s) {
    const int t = s * 256 + tid;
    if (r1[s]) loc1[t] = pre1[s][w] + r1[s] - 1;
    if (r2[s]) loc2[t] = c1 + pre2[s][w] + r2[s] - 1;
  }
}

// ---------------- K3: computed fill — ONE pass writes the entire output -----
// out[0]=l_aux; combine=[t][e][c] at 1+idx; dispatch at 1+COMB+idx.
// Element value derived from per-token metadata; capacity drop is implicit
// (c==loc unreachable when loc>=256). 2048 blocks x 256 thr x 128 f32x4 iters.
__global__ __launch_bounds__(256) void k_fill(const int* __restrict__ e1,
    const int* __restrict__ e2, const int* __restrict__ l1,
    const int* __restrict__ l2, const float* __restrict__ g1,
    const float* __restrict__ g2, const float* __restrict__ gsum,
    const int* __restrict__ counts1, float* __restrict__ out) {
  const int tid = threadIdx.x;
  const int bid = blockIdx.x;

  float laux = 0.f;
  if (bid == 0 && tid < 64) {  // wave 0: l_aux (all lanes end with the value)
    float v = gsum[tid] * (float)counts1[tid];
#pragma unroll
    for (int off = 32; off > 0; off >>= 1) v += __shfl_xor(v, off);
    laux = v * (1.0f / 1048576.0f);
  }

  f32x4* o4 = reinterpret_cast<f32x4*>(out);
  size_t ch = (size_t)bid * 32768 + tid;     // 128 iters, stride 256
  for (int it = 0; it < 128; ++it, ch += 256) {
    const size_t g0 = ch * 4;
    f32x4 v = {0.f, 0.f, 0.f, 0.f};
#pragma unroll
    for (int k = 0; k < 4; ++k) {
      const size_t g = g0 + k;
      float val = 0.f;
      if (g == 0) {
        val = laux;
      } else {
        const size_t gm = g - 1;
        const bool disp = gm >= COMB_ELEMS;
        const uint32_t idx = (uint32_t)(disp ? gm - COMB_ELEMS : gm);
        const int t = idx >> 14;
        const int e = (idx >> 8) & 63;
        const int c = idx & 255;
        const int a = e1[t], b = e2[t];
        const int la = l1[t], lb = l2[t];
        const bool h1 = (e == a) & (c == la);   // la>=256 can't match c<256
        const bool h2 = (e == b) & (c == lb);
        if (h1 | h2) {
          if (disp) {
            val = 1.0f;
          } else {
            const float ga = (la < CAP) ? g1[t] : 0.f;
            const float gb = (lb < CAP) ? g2[t] : 0.f;
            const float denom = fmaxf(ga + gb, 1.1920929e-07f);
            val = (h1 ? ga : gb) / denom;
          }
        }
      }
      v[k] = val;
    }
    __builtin_nontemporal_store(v, &o4[ch]);
  }

  if (bid == 0 && tid == 0) {  // tail element g = 268435456 (dispatch idx COMB-1)
    const uint32_t idx = (uint32_t)(COMB_ELEMS - 1);  // t=8191,e=63,c=255
    const int t = idx >> 14, e = (idx >> 8) & 63, c = idx & 255;
    const bool hit = (e == e1[t] && c == l1[t]) || (e == e2[t] && c == l2[t]);
    out[2 * COMB_ELEMS] = hit ? 1.0f : 0.f;
  }
}

extern "C" void kernel_launch(void* const* d_in, const int* in_sizes, int n_in,
                              void* d_out, int out_size, void* d_ws, size_t ws_size,
                              hipStream_t stream) {
  const float* x = (const float*)d_in[0];
  const float* wg = (const float*)d_in[1];
  float* out = (float*)d_out;

  int*   e1      = (int*)d_ws;                // 8192 i32
  int*   e2      = e1 + TOKENS;
  int*   loc1    = e2 + TOKENS;
  int*   loc2    = loc1 + TOKENS;
  int*   counts1 = loc2 + TOKENS;             // 64
  float* g1      = (float*)(counts1 + 64);    // 8192 f32
  float* g2      = g1 + TOKENS;
  float* gsum    = g2 + TOKENS;               // 64
  float* gpart   = gsum + 64;                 // 256*64 f32

  k_gemm_gate<<<GEMM_BLOCKS, 256, 0, stream>>>(x, wg, e1, e2, g1, g2, gpart);
  k_scan<<<EXPERTS, 256, 0, stream>>>(e1, e2, gpart, loc1, loc2, counts1, gsum);
  k_fill<<<FILL_BLOCKS, 256, 0, stream>>>(e1, e2, loc1, loc2, g1, g2, gsum, counts1, out);
}

// Round 9
// 1127.246 us; speedup vs baseline: 1.0257x; 1.0257x over previous
//
#include <hip/hip_runtime.h>
#include <hip/hip_bf16.h>
#include <stdint.h>

#define TOKENS 8192
#define DIM 2048
#define EXPERTS 64
#define CAP 256
#define COMB_ELEMS ((size_t)TOKENS * EXPERTS * CAP)  // 134217728
#define OUT_ELEMS (1 + 2 * COMB_ELEMS)               // 268435457

#define GEMM_BLOCKS 256
#define ZERO_BLOCKS 2048

typedef float f32x4 __attribute__((ext_vector_type(4)));

// ---------------- threefry2x32 (exact JAX semantics) ----------------
__device__ __forceinline__ void tf_round(uint32_t& a, uint32_t& b, int r) {
  a += b;
  b = (b << r) | (b >> (32 - r));
  b ^= a;
}

__device__ __forceinline__ void threefry2x32(uint32_t k0, uint32_t k1,
                                             uint32_t x0, uint32_t x1,
                                             uint32_t& o0, uint32_t& o1) {
  const uint32_t ks0 = k0, ks1 = k1, ks2 = k0 ^ k1 ^ 0x1BD11BDAu;
  x0 += ks0; x1 += ks1;
  tf_round(x0, x1, 13); tf_round(x0, x1, 15); tf_round(x0, x1, 26); tf_round(x0, x1, 6);
  x0 += ks1; x1 += ks2 + 1u;
  tf_round(x0, x1, 17); tf_round(x0, x1, 29); tf_round(x0, x1, 16); tf_round(x0, x1, 24);
  x0 += ks2; x1 += ks0 + 2u;
  tf_round(x0, x1, 13); tf_round(x0, x1, 15); tf_round(x0, x1, 26); tf_round(x0, x1, 6);
  x0 += ks0; x1 += ks1 + 3u;
  tf_round(x0, x1, 17); tf_round(x0, x1, 29); tf_round(x0, x1, 16); tf_round(x0, x1, 24);
  x0 += ks1; x1 += ks2 + 4u;
  tf_round(x0, x1, 13); tf_round(x0, x1, 15); tf_round(x0, x1, 26); tf_round(x0, x1, 6);
  x0 += ks2; x1 += ks0 + 5u;
  o0 = x0; o1 = x1;
}

// ---------------- K1: fused {GEMM+gate} (blocks 0..255) + {zero} (256..2303) --
// Zero path: contiguous 512 KB chunk per block (DRAM/fill-shaped), nt stores.
// GEMM: A staged transposed (xst[k][token], stride 34 -> 8B-aligned b64 reads),
// B staged transposed (wt[k][expert] -> b128 reads).
__global__ __launch_bounds__(256) void k_fused(const float* __restrict__ x,
                                               const float* __restrict__ wg,
                                               float* __restrict__ out,
                                               int* __restrict__ e1, int* __restrict__ e2,
                                               float* __restrict__ g1, float* __restrict__ g2,
                                               float* __restrict__ gpart) {
  __shared__ float xst[32][34];    // [k][token], stride 34 keeps b64 aligned
  __shared__ float wt[32][64];     // [k][expert]; reused as score[t][e]
  __shared__ float gpl[4][64];

  const int tid = threadIdx.x;

  if (blockIdx.x >= GEMM_BLOCKS) {
    // contiguous chunk: block zb owns f32x4 [zb*32768, (zb+1)*32768)
    f32x4* o4 = reinterpret_cast<f32x4*>(out);
    const int zb = blockIdx.x - GEMM_BLOCKS;
    size_t i = (size_t)zb * 32768 + tid;
    const f32x4 z = {0.f, 0.f, 0.f, 0.f};
#pragma unroll 8
    for (int it = 0; it < 128; ++it, i += 256)
      __builtin_nontemporal_store(z, &o4[i]);
    if (zb == 0 && tid == 0) out[2 * COMB_ELEMS] = 0.f;  // tail element
    return;
  }

  // ---- GEMM path: tile 32 tokens x 64 experts, BK=32 ----
  const int tok0 = blockIdx.x * 32;
  const int e0 = (tid & 15) * 4;
  const int t0 = (tid >> 4) * 2;

  const int xr = tid >> 3;             // token 0..31
  const int xc = (tid & 7) << 2;       // k col (float4)
  const int wr = tid >> 2;             // expert 0..63
  const int wc = (tid & 3) << 3;       // k col (2 float4s)

  const float* xp = x + (size_t)(tok0 + xr) * DIM + xc;
  const float* wp = wg + (size_t)wr * DIM + wc;

  float4 xv  = *reinterpret_cast<const float4*>(xp);
  float4 wv0 = *reinterpret_cast<const float4*>(wp);
  float4 wv1 = *reinterpret_cast<const float4*>(wp + 4);

  float acc[2][4] = {{0.f, 0.f, 0.f, 0.f}, {0.f, 0.f, 0.f, 0.f}};

  for (int k0 = 0; k0 < DIM; k0 += 32) {
    xst[xc + 0][xr] = xv.x; xst[xc + 1][xr] = xv.y;
    xst[xc + 2][xr] = xv.z; xst[xc + 3][xr] = xv.w;
    wt[wc + 0][wr] = wv0.x; wt[wc + 1][wr] = wv0.y;
    wt[wc + 2][wr] = wv0.z; wt[wc + 3][wr] = wv0.w;
    wt[wc + 4][wr] = wv1.x; wt[wc + 5][wr] = wv1.y;
    wt[wc + 6][wr] = wv1.z; wt[wc + 7][wr] = wv1.w;
    __syncthreads();
    if (k0 + 32 < DIM) {  // register prefetch overlaps compute
      xv  = *reinterpret_cast<const float4*>(xp + k0 + 32);
      wv0 = *reinterpret_cast<const float4*>(wp + k0 + 32);
      wv1 = *reinterpret_cast<const float4*>(wp + k0 + 36);
    }
#pragma unroll
    for (int kk = 0; kk < 32; ++kk) {
      const float4 b = *reinterpret_cast<const float4*>(&wt[kk][e0]);   // b128
      const float2 a = *reinterpret_cast<const float2*>(&xst[kk][t0]);  // b64
      acc[0][0] = fmaf(a.x, b.x, acc[0][0]);
      acc[0][1] = fmaf(a.x, b.y, acc[0][1]);
      acc[0][2] = fmaf(a.x, b.z, acc[0][2]);
      acc[0][3] = fmaf(a.x, b.w, acc[0][3]);
      acc[1][0] = fmaf(a.y, b.x, acc[1][0]);
      acc[1][1] = fmaf(a.y, b.y, acc[1][1]);
      acc[1][2] = fmaf(a.y, b.z, acc[1][2]);
      acc[1][3] = fmaf(a.y, b.w, acc[1][3]);
    }
    __syncthreads();
  }

  // scores -> LDS (reuse wt as score[token][expert])
#pragma unroll
  for (int i = 0; i < 2; ++i)
    *reinterpret_cast<float4*>(&wt[t0 + i][e0]) =
        make_float4(acc[i][0], acc[i][1], acc[i][2], acc[i][3]);
  __syncthreads();

  // ---- gate epilogue: wave w handles local tokens w*8 .. w*8+7 ----
  const int w = tid >> 6;
  const int lane = tid & 63;
  float colsum = 0.f;
  for (int lt = w * 8; lt < w * 8 + 8; ++lt) {
    const int t = tok0 + lt;
    const float logit = wt[lt][lane];

    float m = logit;
#pragma unroll
    for (int off = 32; off > 0; off >>= 1) m = fmaxf(m, __shfl_xor(m, off));
    const float ex = expf(logit - m);
    float s = ex;
#pragma unroll
    for (int off = 32; off > 0; off >>= 1) s += __shfl_xor(s, off);
    const float gate = ex / s;
    colsum += gate;

    float v1 = logit; int i1 = lane;
#pragma unroll
    for (int off = 32; off > 0; off >>= 1) {
      const float ov = __shfl_xor(v1, off);
      const int oi = __shfl_xor(i1, off);
      if (ov > v1 || (ov == v1 && oi < i1)) { v1 = ov; i1 = oi; }
    }

    // gumbel(key=42), jax_threefry_partitionable: counter=(0,i), bits=o0^o1
    const uint32_t i_flat = (uint32_t)t * 64u + (uint32_t)lane;
    uint32_t b0, b1;
    threefry2x32(0u, 42u, 0u, i_flat, b0, b1);
    const uint32_t bits = b0 ^ b1;
    float u = __uint_as_float((bits >> 9) | 0x3f800000u) - 1.0f;
    u += 1.17549435e-38f;
    const float gum = -logf(-logf(u));
    const float noisy = (lane == i1) ? -__builtin_inff() : (logit + gum);

    float v2 = noisy; int i2 = lane;
#pragma unroll
    for (int off = 32; off > 0; off >>= 1) {
      const float ov = __shfl_xor(v2, off);
      const int oi = __shfl_xor(i2, off);
      if (ov > v2 || (ov == v2 && oi < i2)) { v2 = ov; i2 = oi; }
    }

    const float gate1 = __shfl(gate, i1);
    const float gate2 = __shfl(gate, i2);
    if (lane == 0) { e1[t] = i1; e2[t] = i2; g1[t] = gate1; g2[t] = gate2; }
  }
  gpl[w][lane] = colsum;
  __syncthreads();
  if (w == 0)
    gpart[(size_t)blockIdx.x * 64 + lane] =
        (gpl[0][lane] + gpl[1][lane]) + (gpl[2][lane] + gpl[3][lane]);
}

// ---------------- K2: per-expert prefix ranks (3-sync) + gsum ----------------
__global__ __launch_bounds__(256) void k_scan(const int* __restrict__ e1,
    const int* __restrict__ e2, const float* __restrict__ gpart,
    int* __restrict__ loc1, int* __restrict__ loc2,
    int* __restrict__ counts1, float* __restrict__ gsum) {
  const int e = blockIdx.x;
  const int tid = threadIdx.x;
  const int lane = tid & 63;
  const int w = tid >> 6;
  __shared__ int wt1[32][4], wt2[32][4];
  __shared__ int pre1[32][4], pre2[32][4];
  __shared__ int c1tot;
  __shared__ float gw[4];

  float gp = gpart[(size_t)tid * 64 + e];
#pragma unroll
  for (int off = 32; off > 0; off >>= 1) gp += __shfl_xor(gp, off);
  if (lane == 0) gw[w] = gp;

  const uint64_t ltm = (lane == 0) ? 0ull : ((~0ull) >> (64 - lane));

  int r1[32], r2[32];
#pragma unroll
  for (int s = 0; s < 32; ++s) {
    const int t = s * 256 + tid;
    const bool q1 = (e1[t] == e);
    const bool q2 = (e2[t] == e);
    const uint64_t m1 = __ballot(q1);
    const uint64_t m2 = __ballot(q2);
    r1[s] = q1 ? (int)__popcll(m1 & ltm) + 1 : 0;
    r2[s] = q2 ? (int)__popcll(m2 & ltm) + 1 : 0;
    if (lane == 0) { wt1[s][w] = (int)__popcll(m1); wt2[s][w] = (int)__popcll(m2); }
  }
  __syncthreads();

  if (tid == 0) gsum[e] = (gw[0] + gw[1]) + (gw[2] + gw[3]);

  if (w == 0) {
    {
      int va = wt1[lane >> 2][lane & 3];
      int vb = wt1[(64 + lane) >> 2][(64 + lane) & 3];
      int sa = va, sb = vb;
#pragma unroll
      for (int d = 1; d < 64; d <<= 1) {
        const int t1 = __shfl_up(sa, d);
        const int t2 = __shfl_up(sb, d);
        if (lane >= d) { sa += t1; sb += t2; }
      }
      const int tot_a = __shfl(sa, 63);
      pre1[lane >> 2][lane & 3] = sa - va;
      pre1[(64 + lane) >> 2][(64 + lane) & 3] = tot_a + sb - vb;
      if (lane == 63) c1tot = tot_a + sb;
    }
    {
      int va = wt2[lane >> 2][lane & 3];
      int vb = wt2[(64 + lane) >> 2][(64 + lane) & 3];
      int sa = va, sb = vb;
#pragma unroll
      for (int d = 1; d < 64; d <<= 1) {
        const int t1 = __shfl_up(sa, d);
        const int t2 = __shfl_up(sb, d);
        if (lane >= d) { sa += t1; sb += t2; }
      }
      const int tot_a = __shfl(sa, 63);
      pre2[lane >> 2][lane & 3] = sa - va;
      pre2[(64 + lane) >> 2][(64 + lane) & 3] = tot_a + sb - vb;
    }
  }
  __syncthreads();

  const int c1 = c1tot;
  if (tid == 0) counts1[e] = c1;

#pragma unroll
  for (int s = 0; s < 32; ++s) {
    const int t = s * 256 + tid;
    if (r1[s]) loc1[t] = pre1[s][w] + r1[s] - 1;
    if (r2[s]) loc2[t] = c1 + pre2[s][w] + r2[s] - 1;
  }
}

// ---------------- K3: sparse scatter + l_aux (block 0) ----------------
__global__ __launch_bounds__(256) void k_scatter(const int* __restrict__ e1,
    const int* __restrict__ e2, const float* __restrict__ g1,
    const float* __restrict__ g2, const int* __restrict__ loc1,
    const int* __restrict__ loc2, const float* __restrict__ gsum,
    const int* __restrict__ counts1, float* __restrict__ out) {
  const int tid = threadIdx.x;
  if (blockIdx.x == 0 && tid < 64) {
    float v = gsum[tid] * (float)counts1[tid];
#pragma unroll
    for (int off = 32; off > 0; off >>= 1) v += __shfl_xor(v, off);
    if (tid == 0) out[0] = v * (1.0f / 1048576.0f);
  }
  const int t = blockIdx.x * 256 + tid;
  const int a = e1[t], b = e2[t];
  const int l1 = loc1[t], l2 = loc2[t];
  const bool k1 = l1 < CAP;
  const bool k2 = l2 < CAP;
  const float ga = k1 ? g1[t] : 0.f;
  const float gb = k2 ? g2[t] : 0.f;
  const float denom = fmaxf(ga + gb, 1.1920929e-07f);
  float* __restrict__ combine = out + 1;
  float* __restrict__ dispatch = out + 1 + COMB_ELEMS;
  if (k1) {
    const size_t idx = ((size_t)t * EXPERTS + a) * CAP + l1;
    combine[idx] = ga / denom;
    dispatch[idx] = 1.0f;
  }
  if (k2) {
    const size_t idx = ((size_t)t * EXPERTS + b) * CAP + l2;
    combine[idx] = gb / denom;
    dispatch[idx] = 1.0f;
  }
}

extern "C" void kernel_launch(void* const* d_in, const int* in_sizes, int n_in,
                              void* d_out, int out_size, void* d_ws, size_t ws_size,
                              hipStream_t stream) {
  const float* x = (const float*)d_in[0];
  const float* wg = (const float*)d_in[1];
  float* out = (float*)d_out;

  int*   e1      = (int*)d_ws;                // 8192 i32
  int*   e2      = e1 + TOKENS;
  int*   loc1    = e2 + TOKENS;
  int*   loc2    = loc1 + TOKENS;
  int*   counts1 = loc2 + TOKENS;             // 64
  float* g1      = (float*)(counts1 + 64);    // 8192 f32
  float* g2      = g1 + TOKENS;
  float* gsum    = g2 + TOKENS;               // 64
  float* gpart   = gsum + 64;                 // 256*64 f32

  k_fused<<<GEMM_BLOCKS + ZERO_BLOCKS, 256, 0, stream>>>(x, wg, out, e1, e2, g1, g2, gpart);
  k_scan<<<EXPERTS, 256, 0, stream>>>(e1, e2, gpart, loc1, loc2, counts1, gsum);
  k_scatter<<<TOKENS / 256, 256, 0, stream>>>(e1, e2, g1, g2, loc1, loc2, gsum, counts1, out);
}